// Round 6
// baseline (599.490 us; speedup 1.0000x reference)
//
#include <hip/hip_runtime.h>
#include <hip/hip_bf16.h>

// SA_fusion: B=4, C=512, H=W=64 (HW=4096), fp32 in/out.
// R12: gemm256 -> m201 geometry. R11 counters: MfmaUtil 15%, conflicts 0,
// HBM 25% -- limiter is LDS-bytes-per-MFMA (wave tile 128x32 = 640B/MFMA).
// Now BM=BN=256, 8 waves 2Mx4N, wave tile 128x64, acc[8][4]: a[8] reused
// over 4 b-frags -> 12 ds_read_b128 per 32 MFMA (2x reuse). LDS = 8 units
// (dbuf2 x {A,B} x {h0,h1}) x 16KB = 128KB. Stage unit = operand-half =
// 2 g2l16/thread. Schedule per tile t: p0:Ah1(t+1) p1:Bh0(t+1) p2:Bh1(t+1)
// p3:Ah0(t+2)+vmcnt(2). Ledger: unit slot = same unit of t-2; A(t-1) last
// read at (t-1)p2, B(t-1) at (t-1)p3 -> every stage >=1 barrier after last
// read of its slot; every unit lands >=2 phases before first read; wait is
// counted vmcnt(2) once per tile (drain only at tail). T2 swizzle + T5
// setprio + 2 barriers/phase unchanged from R10/R11 (proven). PV stays
// split-4 fp32 + reduce4 (no numerics change).

typedef _Float16 f16_t;
typedef _Float16 f16x8 __attribute__((ext_vector_type(8)));
typedef float f32x4 __attribute__((ext_vector_type(4)));

#define C_DIM 512
#define HW_DIM 4096
#define NBATCH 4
#define CHW (512L * 4096L)

__device__ inline f32x4 mfma_f16(f16x8 a, f16x8 b, f32x4 c) {
    return __builtin_amdgcn_mfma_f32_16x16x32_f16(a, b, c, 0, 0, 0);
}

// async 16B/lane global->LDS; lane i lands at base + i*16 (wave-uniform base).
__device__ inline void g2l16(const f16_t* g, f16_t* l) {
    auto gp = (const __attribute__((address_space(1))) uint32_t*)(uintptr_t)g;
    auto lp = (__attribute__((address_space(3))) uint32_t*)(uint32_t)(uintptr_t)l;
    __builtin_amdgcn_global_load_lds(gp, lp, 16, 0, 0);
}

// counted vmcnt wait, compile-time immediate, memory-clobbered.
template<int N> __device__ inline void vmwait() {
    static_assert(N == 0 || N == 2, "add vmcnt case");
    if constexpr (N == 0) asm volatile("s_waitcnt vmcnt(0)" ::: "memory");
    else                  asm volatile("s_waitcnt vmcnt(2)" ::: "memory");
}

__device__ inline void barrier_mem() {
    asm volatile("s_barrier" ::: "memory");
    __builtin_amdgcn_sched_barrier(0);
}

// ---------------- stats: mean + rstd (unbiased var, ddof=1) per (b,c) --------
__global__ __launch_bounds__(256) void stats_kernel(
    const float* __restrict__ xc, const float* __restrict__ xs,
    float* __restrict__ meanc, float* __restrict__ rstdc,
    float* __restrict__ means, float* __restrict__ rstds)
{
    int id = blockIdx.x;
    int bc = id & 2047;
    const float4* x = (const float4*)((id < 2048 ? xc : xs) + (size_t)bc * HW_DIM);
    int tid = threadIdx.x;
    float s = 0.f, ss = 0.f;
#pragma unroll
    for (int i = 0; i < 4; i++) {
        float4 v = x[tid + (i << 8)];
        s += v.x + v.y + v.z + v.w;
        ss += v.x * v.x + v.y * v.y + v.z * v.z + v.w * v.w;
    }
#pragma unroll
    for (int o = 32; o; o >>= 1) { s += __shfl_down(s, o); ss += __shfl_down(ss, o); }
    __shared__ float red[8];
    if ((tid & 63) == 0) { red[(tid >> 6) * 2] = s; red[(tid >> 6) * 2 + 1] = ss; }
    __syncthreads();
    if (tid == 0) {
        s  = red[0] + red[2] + red[4] + red[6];
        ss = red[1] + red[3] + red[5] + red[7];
        float mean = s * (1.0f / 4096.0f);
        float var  = (ss - 4096.0f * mean * mean) * (1.0f / 4095.0f);
        float rstd = rsqrtf(var + 1e-5f);
        if (id < 2048) { meanc[bc] = mean; rstdc[bc] = rstd; }
        else           { means[bc] = mean; rstds[bc] = rstd; }
    }
}

// ---------------- weight pack: fp32 -> fp16 + bias copy ----------------------
__global__ __launch_bounds__(256) void pack_w4_kernel(
    const float* __restrict__ w0, const float* __restrict__ w1,
    const float* __restrict__ w2, const float* __restrict__ w3,
    f16_t* __restrict__ h0, f16_t* __restrict__ h1,
    f16_t* __restrict__ h2, f16_t* __restrict__ h3,
    const float* __restrict__ bb0, const float* __restrict__ bb1,
    const float* __restrict__ bb2, const float* __restrict__ bb3,
    float* __restrict__ biasws)
{
    int which = blockIdx.y;
    const float* w = which == 0 ? w0 : which == 1 ? w1 : which == 2 ? w2 : w3;
    f16_t* h = which == 0 ? h0 : which == 1 ? h1 : which == 2 ? h2 : h3;
    const float* bs = which == 0 ? bb0 : which == 1 ? bb1 : which == 2 ? bb2 : bb3;
    int i = blockIdx.x * 256 + threadIdx.x;
    h[i] = (f16_t)w[i];
    if (i < C_DIM) biasws[which * C_DIM + i] = bs[i];
}

// ---------------- input pack: (B,C,HW) fp32 -> (B,HW,C) fp16 -----------------
__global__ __launch_bounds__(256) void pack_T_kernel(
    const float* __restrict__ xc, const float* __restrict__ xs,
    const float* __restrict__ meanc, const float* __restrict__ rstdc,
    const float* __restrict__ means, const float* __restrict__ rstds,
    f16_t* __restrict__ ch, f16_t* __restrict__ sh, f16_t* __restrict__ sraw)
{
    __shared__ float tile[32][33];
    int z = blockIdx.z;
    int b = z & 3, src = z >> 2;
    const float* x    = (src == 0) ? xc : xs;
    const float* mean = (src == 0) ? meanc : means;
    const float* rstd = (src == 0) ? rstdc : rstds;

    int c0 = blockIdx.y * 32, p0 = blockIdx.x * 32;
    int tp = threadIdx.x & 31, tc8 = threadIdx.x >> 5;
    const float* xb = x + ((size_t)b * C_DIM + c0) * HW_DIM + p0;
#pragma unroll
    for (int it = 0; it < 4; it++) {
        int c = tc8 + it * 8;
        tile[c][tp] = xb[(size_t)c * HW_DIM + tp];
    }
    __syncthreads();
    int wc = threadIdx.x & 31, wp8 = threadIdx.x >> 5;
    float m = mean[b * C_DIM + c0 + wc];
    float r = rstd[b * C_DIM + c0 + wc];
    size_t obase = ((size_t)b * HW_DIM + p0) * C_DIM + c0;
    f16_t* ohb = ((src == 0) ? ch : sh) + obase;
    f16_t* srb = sraw + obase;
#pragma unroll
    for (int it = 0; it < 4; it++) {
        int p = wp8 + it * 8;
        float v = tile[wc][p];
        ohb[(size_t)p * C_DIM + wc] = (f16_t)((v - m) * r);
        if (src == 1) srb[(size_t)p * C_DIM + wc] = (f16_t)v;
    }
}

// ---------------- row softmax: S fp32 (4096x4096) -> P fp16, normalized ------
__global__ __launch_bounds__(256) void softmax_rows(
    const float* __restrict__ S, f16_t* __restrict__ P)
{
    int row = blockIdx.x;
    int tid = threadIdx.x;
    int wave = tid >> 6, lane = tid & 63;
    const float4* sr = (const float4*)(S + (size_t)row * HW_DIM);
    float4 v[4];
    float mx = -3.4e38f;
#pragma unroll
    for (int i = 0; i < 4; i++) {
        v[i] = sr[tid + (i << 8)];
        mx = fmaxf(mx, fmaxf(fmaxf(v[i].x, v[i].y), fmaxf(v[i].z, v[i].w)));
    }
#pragma unroll
    for (int o = 32; o; o >>= 1) mx = fmaxf(mx, __shfl_down(mx, o));
    __shared__ float red[4];
    if (lane == 0) red[wave] = mx;
    __syncthreads();
    mx = fmaxf(fmaxf(red[0], red[1]), fmaxf(red[2], red[3]));
    float sum = 0.f;
#pragma unroll
    for (int i = 0; i < 4; i++) {
        v[i].x = __expf(v[i].x - mx); v[i].y = __expf(v[i].y - mx);
        v[i].z = __expf(v[i].z - mx); v[i].w = __expf(v[i].w - mx);
        sum += v[i].x + v[i].y + v[i].z + v[i].w;
    }
#pragma unroll
    for (int o = 32; o; o >>= 1) sum += __shfl_down(sum, o);
    __syncthreads();
    if (lane == 0) red[wave] = sum;
    __syncthreads();
    sum = red[0] + red[1] + red[2] + red[3];
    float inv = 1.0f / sum;
    uint2* pr = (uint2*)(P + (size_t)row * HW_DIM);
#pragma unroll
    for (int i = 0; i < 4; i++) {
        union { uint2 u; f16_t h[4]; } o;
        o.h[0] = (f16_t)(v[i].x * inv); o.h[1] = (f16_t)(v[i].y * inv);
        o.h[2] = (f16_t)(v[i].z * inv); o.h[3] = (f16_t)(v[i].w * inv);
        pr[tid + (i << 8)] = o.u;
    }
}

// ---------------- split-K reduce: frsT[q][c] = f16(sum of 4 fp32 partials) ---
__global__ __launch_bounds__(256) void reduce4_kernel(
    const float* __restrict__ part, f16_t* __restrict__ out)
{
    size_t i = (size_t)blockIdx.x * 256 + threadIdx.x;   // float4 index
    const float4* p0 = (const float4*)part;
    const float4* p1 = (const float4*)(part + CHW);
    const float4* p2 = (const float4*)(part + 2 * CHW);
    const float4* p3 = (const float4*)(part + 3 * CHW);
    float4 a = p0[i], b = p1[i], c = p2[i], d = p3[i];
    union { uint2 u; f16_t h[4]; } o;
    o.h[0] = (f16_t)(a.x + b.x + c.x + d.x);
    o.h[1] = (f16_t)(a.y + b.y + c.y + d.y);
    o.h[2] = (f16_t)(a.z + b.z + c.z + d.z);
    o.h[3] = (f16_t)(a.w + b.w + c.w + d.w);
    ((uint2*)out)[i] = o.u;
}

// ================= gemm256: 256x256 phase-pipelined NT GEMM ==================
// C[m][n] = sum_k A[m][k]*B[n][k]. BM=BN=256, BK=64, 512 threads = 8 waves
// (2M x 4N), per-wave output 128x64, acc[8][4]. K = NT*64.
// LDS: 8 units of 128rows x 64k f16 (16KB): unit idx = (t&1)*4 + isB*2 + h.
// Per tile: 4 phases (ks,nh): nh=0 loads a[8]+b[2] (10 reads), nh=1 b[2];
// 16 MFMA per phase between 2 barriers with setprio. Stage unit schedule
// (see header ledger): p0 Ah1(t+1), p1 Bh0(t+1), p2 Bh1(t+1), p3 Ah0(t+2)
// then vmcnt(2). T2 swizzle: LDS granule g holds src granule g^(row&7) via
// pre-swizzled global source (linear g2l16 dest); reads XOR by fr&7.
// EPI: 0 fp32 [m][n] (+bias,+resid); 1 f16 [m][n] (+bias);
//      3 f16 T [n][m] (+bias); 4 fp32 T [n][m] (no bias).
// QK: z encodes (sel=z>>2, batch=z&3).
template<int EPI, bool QK, int NT, int CHX, int CHY>
__global__ __launch_bounds__(512, 2) void gemm256(
    const f16_t* __restrict__ Ah, const f16_t* __restrict__ Bh,
    void* __restrict__ Cout0, const float* __restrict__ bias,
    const float* __restrict__ resid,
    int lda, int ldc,
    long sAz, long sBz, long sCz, long sRz, long sAw, long sBw, long sCw)
{
    constexpr int UNIT = 128 * 64;                   // 8192 f16 = 16 KB
    __shared__ __align__(16) f16_t smem[8 * UNIT];   // 128 KB

    // ---- XCD chunk swizzle (bijective; nwg % 8 == 0, pow2 chunks) ----
    int bx, by, bz;
    {
        const int nbx = gridDim.x, nby = gridDim.y, nbz = gridDim.z;
        const int lin = ((int)blockIdx.z * nby + blockIdx.y) * nbx + blockIdx.x;
        const int nwg = nbx * nby * nbz;
        const int cpx = nwg >> 3;
        const int logical = (lin & 7) * cpx + (lin >> 3);
        constexpr int CHB = CHX * CHY;
        const int chunk  = logical / CHB;
        const int within = logical % CHB;
        const int cx = within % CHX, cy = within / CHX;
        const int chunks_x = nbx / CHX;
        const int chx = chunk % chunks_x;
        int tt = chunk / chunks_x;
        const int chunks_y = nby / CHY;
        bz = tt / chunks_y;
        by = (tt % chunks_y) * CHY + cy;
        bx = chx * CHX + cx;
    }

    const int tid  = threadIdx.x;
    const int wave = tid >> 6, lane = tid & 63;
    const int wm = (wave >> 2) * 128;    // M-group (also = A-half * 128)
    const int wn = (wave & 3) * 64;      // N-group
    const int fr = lane & 15;
    const int g16 = lane >> 4;           // 0..3
    const int key = fr & 7;              // read-side swizzle key
    const int ha  = wave >> 2;           // wave's A-half
    const int hb  = wn >> 7;             // wave's B-half
    const int rB  = wn - hb * 128;       // row base within B-half (0 or 64)

    const int z   = QK ? (bz & 3) : bz;
    const int sel = QK ? (bz >> 2) : 0;
    const f16_t* Az = Ah + (size_t)z * sAz + (size_t)sel * sAw;
    const f16_t* Bz = Bh + (size_t)z * sBz + (size_t)sel * sBw;
    const float* biasp = bias ? (bias + (QK ? sel * C_DIM : 0)) : nullptr;
    const long mBlock = (long)by * 256;
    const long nBlock = (long)bx * 256;

    // staging: unit = 128 rows x 128B; per thread 2 instrs (q=0,1), each
    // wave-instr covers 8 rows; row = q*64 + wave*8 + (lane>>3); LDS granule
    // lane&7 holds pre-swizzled source granule (lane&7)^(lane>>3).
    const int srow8 = lane >> 3;
    const int gsrc  = ((lane & 7) ^ srow8) * 8;      // f16 elems
    const f16_t* aRow[2][2]; const f16_t* bRow[2][2];
#pragma unroll
    for (int h = 0; h < 2; h++)
#pragma unroll
        for (int q = 0; q < 2; q++) {
            long r = q * 64 + wave * 8 + srow8;
            aRow[h][q] = Az + (size_t)(mBlock + h * 128 + r) * lda + gsrc;
            bRow[h][q] = Bz + (size_t)(nBlock + h * 128 + r) * lda + gsrc;
        }
    const int dst0 = wave * 512;           // (0*64 + wave*8)*64
    const int dst1 = 4096 + wave * 512;    // (1*64 + wave*8)*64

    auto stageU = [&](int t, int isB, int h) {
        f16_t* ub = smem + ((t & 1) * 4 + isB * 2 + h) * UNIT;
        const long k0 = (long)t * 64;
        if (isB) {
            g2l16(bRow[h][0] + k0, ub + dst0);
            g2l16(bRow[h][1] + k0, ub + dst1);
        } else {
            g2l16(aRow[h][0] + k0, ub + dst0);
            g2l16(aRow[h][1] + k0, ub + dst1);
        }
    };

    f32x4 acc[8][4];
#pragma unroll
    for (int i = 0; i < 8; i++)
#pragma unroll
        for (int j = 0; j < 4; j++) acc[i][j] = (f32x4){0.f, 0.f, 0.f, 0.f};

    // prologue: all of tile 0 + Ah0(1); wait tile 0 (Ah0(1) stays in flight)
    stageU(0, 0, 0); stageU(0, 0, 1); stageU(0, 1, 0); stageU(0, 1, 1);
    if (NT > 1) stageU(1, 0, 0);
    vmwait<2>();
    barrier_mem();

#pragma unroll
    for (int t = 0; t < NT; ++t) {
        const f16_t* bufA = smem + ((t & 1) * 4 + ha) * UNIT;
        const f16_t* bufB = smem + ((t & 1) * 4 + 2 + hb) * UNIT;
#pragma unroll
        for (int ks = 0; ks < 2; ++ks) {
            const int gr = ((ks * 4 + g16) ^ key) * 8;   // swizzled granule
            f16x8 a[8], b0, b1;
            // ---- phase nh=0: loads a[8] + b[0..1] ----
#pragma unroll
            for (int mi = 0; mi < 8; mi++)
                a[mi] = *reinterpret_cast<const f16x8*>(
                    bufA + (mi * 16 + fr) * 64 + gr);
            b0 = *reinterpret_cast<const f16x8*>(bufB + (rB + fr) * 64 + gr);
            b1 = *reinterpret_cast<const f16x8*>(bufB + (rB + 16 + fr) * 64 + gr);
            if (ks == 0) { if (t + 1 < NT) stageU(t + 1, 0, 1); }   // p0: Ah1
            else         { if (t + 1 < NT) stageU(t + 1, 1, 1); }   // p2: Bh1
            barrier_mem();
            __builtin_amdgcn_s_setprio(1);
#pragma unroll
            for (int mi = 0; mi < 8; mi++) {
                acc[mi][0] = mfma_f16(a[mi], b0, acc[mi][0]);
                acc[mi][1] = mfma_f16(a[mi], b1, acc[mi][1]);
            }
            __builtin_amdgcn_s_setprio(0);
            barrier_mem();
            // ---- phase nh=1: loads b[2..3], reuse a[8] ----
            b0 = *reinterpret_cast<const f16x8*>(bufB + (rB + 32 + fr) * 64 + gr);
            b1 = *reinterpret_cast<const f16x8*>(bufB + (rB + 48 + fr) * 64 + gr);
            if (ks == 0) { if (t + 1 < NT) stageU(t + 1, 1, 0); }   // p1: Bh0
            else {                                                   // p3: Ah0 + vmcnt
                if (t + 2 < NT) { stageU(t + 2, 0, 0); vmwait<2>(); }
                else if (t + 1 < NT) vmwait<0>();
            }
            barrier_mem();
            __builtin_amdgcn_s_setprio(1);
#pragma unroll
            for (int mi = 0; mi < 8; mi++) {
                acc[mi][2] = mfma_f16(a[mi], b0, acc[mi][2]);
                acc[mi][3] = mfma_f16(a[mi], b1, acc[mi][3]);
            }
            __builtin_amdgcn_s_setprio(0);
            barrier_mem();
        }
    }

    // epilogue. D layout: col(n)=lane&15, row(m)=(lane>>4)*4+reg
    const int col  = lane & 15;
    const int rowq = (lane >> 4) * 4;
    const size_t cbase = (size_t)z * sCz + (size_t)sel * sCw;
#pragma unroll
    for (int mi = 0; mi < 8; mi++) {
        const long mb = mBlock + wm + mi * 16 + rowq;
        float bv[4];
#pragma unroll
        for (int r = 0; r < 4; r++) bv[r] = biasp ? biasp[mb + r] : 0.0f;
#pragma unroll
        for (int j2 = 0; j2 < 4; j2++) {
            const long n = nBlock + wn + j2 * 16 + col;
            float v[4];
#pragma unroll
            for (int r = 0; r < 4; r++) v[r] = acc[mi][j2][r] + bv[r];
            if constexpr (EPI == 0) {
                float* O = (float*)Cout0 + cbase;
                const float* R = resid ? (resid + (size_t)z * sRz) : nullptr;
#pragma unroll
                for (int r = 0; r < 4; r++) {
                    size_t off = (size_t)(mb + r) * ldc + n;
                    O[off] = v[r] + (R ? R[off] : 0.0f);
                }
            } else if constexpr (EPI == 1) {
                f16_t* O = (f16_t*)Cout0 + cbase;
#pragma unroll
                for (int r = 0; r < 4; r++) O[(size_t)(mb + r) * ldc + n] = (f16_t)v[r];
            } else if constexpr (EPI == 3) {
                alignas(8) f16_t h[4];
#pragma unroll
                for (int r = 0; r < 4; r++) h[r] = (f16_t)v[r];
                *reinterpret_cast<uint2*>((f16_t*)Cout0 + cbase + (size_t)n * ldc + mb)
                    = *reinterpret_cast<uint2*>(h);
            } else {   // EPI == 4: fp32 transposed partial
                alignas(16) float h[4];
#pragma unroll
                for (int r = 0; r < 4; r++) h[r] = v[r];
                *reinterpret_cast<float4*>((float*)Cout0 + cbase + (size_t)n * ldc + mb)
                    = *reinterpret_cast<float4*>(h);
            }
        }
    }
}

// ---------------------------------------------------------------------------
extern "C" void kernel_launch(void* const* d_in, const int* in_sizes, int n_in,
                              void* d_out, int out_size, void* d_ws, size_t ws_size,
                              hipStream_t stream)
{
    const float* x_fcc = (const float*)d_in[0];
    const float* x_fss = (const float*)d_in[1];
    const float* w1 = (const float*)d_in[2];
    const float* b1 = (const float*)d_in[3];
    const float* w2 = (const float*)d_in[4];
    const float* b2 = (const float*)d_in[5];
    const float* w3 = (const float*)d_in[6];
    const float* b3 = (const float*)d_in[7];
    const float* wrs = (const float*)d_in[8];
    const float* brs = (const float*)d_in[9];
    float* out = (float*)d_out;
    (void)n_in; (void)in_sizes; (void)out_size; (void)ws_size;

    char* base = (char*)d_ws;
    size_t off = 0;
    auto take = [&](size_t bytes) -> char* {
        char* p = base + off;
        off += (bytes + 255) & ~(size_t)255;
        return p;
    };
    const size_t WB = (size_t)C_DIM * C_DIM * sizeof(f16_t);    // 512 KB
    const size_t TB = (size_t)NBATCH * CHW * sizeof(f16_t);     // 16 MB
    const long  TBe = NBATCH * CHW;                             // 8388608 elems

    float* meanc = (float*)take(2048 * 4);
    float* rstdc = (float*)take(2048 * 4);
    float* means = (float*)take(2048 * 4);
    float* rstds = (float*)take(2048 * 4);
    float* biasws = (float*)take(4 * C_DIM * 4);
    f16_t* w1h = (f16_t*)take(WB);
    f16_t* w2h = (f16_t*)take(WB);
    f16_t* w3h = (f16_t*)take(WB);
    f16_t* wrh = (f16_t*)take(WB);
    f16_t* qT = (f16_t*)take(TB);
    f16_t* kT = (f16_t*)take(TB);
    f16_t* vh   = (f16_t*)take(TB);
    f16_t* frsT = (f16_t*)take(TB);
    // 128 MB region. phase-1: xcT(16) xsT(16) xsrT(16) [dead after convs].
    // per-batch: S fp32 [0,64) -> P fp16 [64,96) -> partials fp32 [96,128).
    char* packb = take(8 * TB);
    f16_t* xcT  = (f16_t*)(packb);
    f16_t* xsT  = (f16_t*)(packb + TB);
    f16_t* xsrT = (f16_t*)(packb + 2 * TB);
    float* Smat = (float*)(packb);
    f16_t* Pmat = (f16_t*)(packb + 4 * TB);
    float* Part = (float*)(packb + 6 * TB);
    // total ws unchanged (~194 MB)

    dim3 blk(256);
    dim3 blk5(512);

    // 1. stats
    stats_kernel<<<dim3(4096), blk, 0, stream>>>(x_fcc, x_fss, meanc, rstdc, means, rstds);
    // 2. weight packs + bias copy
    pack_w4_kernel<<<dim3(1024, 4), blk, 0, stream>>>(
        w1, w2, w3, wrs, w1h, w2h, w3h, wrh, b1, b2, b3, brs, biasws);
    // 3. input packs (single style read -> sh + sraw)
    pack_T_kernel<<<dim3(128, 16, 8), blk, 0, stream>>>(
        x_fcc, x_fss, meanc, rstdc, means, rstds, xcT, xsT, xsrT);
    // 4. q+k convs merged: sel 0 = (w1,content)->qT; 1 = (w2,style)->kT
    gemm256<3, true, 8, 8, 2><<<dim3(16, 2, 8), blk5, 0, stream>>>(
        w1h, xcT, qT, biasws, nullptr, C_DIM, C_DIM,
        0L, CHW, CHW, 0L, (long)C_DIM * C_DIM, TBe, TBe);
    // 5. v conv: vh[c][p] f16 +bias
    gemm256<1, false, 8, 8, 2><<<dim3(16, 2, 4), blk5, 0, stream>>>(
        w3h, xsrT, vh, biasws + 2 * C_DIM, nullptr, C_DIM, HW_DIM,
        0L, CHW, CHW, 0L, 0L, 0L, 0L);
    // 6. per-batch attention
    for (int b = 0; b < NBATCH; b++) {
        // scores: S[q][k] fp32 (256 blocks, 1/CU)
        gemm256<0, false, 8, 4, 8><<<dim3(16, 16, 1), blk5, 0, stream>>>(
            qT + (size_t)b * CHW, kT + (size_t)b * CHW,
            Smat, nullptr, nullptr, C_DIM, HW_DIM,
            0L, 0L, 0L, 0L, 0L, 0L, 0L);
        softmax_rows<<<dim3(4096), blk, 0, stream>>>(Smat, Pmat);
        // PV split-4: z = split (k-offset z*1024, NT=16), partial[z] fp32 [q][c]
        gemm256<4, false, 16, 8, 2><<<dim3(16, 2, 4), blk5, 0, stream>>>(
            vh + (size_t)b * CHW, Pmat,
            Part, nullptr, nullptr, HW_DIM, C_DIM,
            1024L, 1024L, CHW, 0L, 0L, 0L, 0L);
        // reduce 4 partials -> fp16 frsT[b]
        reduce4_kernel<<<dim3(CHW / 1024), blk, 0, stream>>>(
            Part, frsT + (size_t)b * CHW);
    }
    // 7. final conv + bias + residual -> fp32 out
    gemm256<0, false, 8, 8, 2><<<dim3(16, 2, 4), blk5, 0, stream>>>(
        wrh, frsT, out, biasws + 3 * C_DIM, x_fcc, C_DIM, HW_DIM,
        0L, CHW, CHW, CHW, 0L, 0L, 0L);
}

// Round 7
// 521.060 us; speedup vs baseline: 1.1505x; 1.1505x over previous
//
#include <hip/hip_runtime.h>
#include <hip/hip_bf16.h>

// SA_fusion: B=4, C=512, H=W=64 (HW=4096), fp32 in/out.
// R13: two engines, each in its proven regime. R12 post-mortem: the 256^2
// dbuf-2 engine collapsed prefetch distance to <1 tile (per-tile vmcnt(2)
// waited on same-tile loads -> full latency exposed, MfmaUtil 4%) AND
// halved v/PV/final grids to 128 blocks (half machine).
//   Engine A gemm256d (scores, qk conv -- full-machine grids): 256^2 dbuf-2
//   with restored depth: stage p0:Bh0(t+1), p1:Bh1(t+1), p3:Ah0+Ah1(t+2);
//   ONE counted vmcnt(4) after p3's MFMA (A staged 5 phases ahead, B 3-4;
//   at the wait exactly tile t+1's units are forced landed, A(t+2) stays
//   in flight). Slot ledger: A(t+2) slot last read t.p2; B(t+1) slot last
//   read (t-1).p3 -- always >=1 barrier between last read and stage.
//   Engine B gemm128r (v conv, PV, final conv): R11's verified BN=128
//   ring-3 vmcnt(6) engine verbatim (full-machine 256-block grids there).

typedef _Float16 f16_t;
typedef _Float16 f16x8 __attribute__((ext_vector_type(8)));
typedef float f32x4 __attribute__((ext_vector_type(4)));

#define C_DIM 512
#define HW_DIM 4096
#define NBATCH 4
#define CHW (512L * 4096L)

__device__ inline f32x4 mfma_f16(f16x8 a, f16x8 b, f32x4 c) {
    return __builtin_amdgcn_mfma_f32_16x16x32_f16(a, b, c, 0, 0, 0);
}

// async 16B/lane global->LDS; lane i lands at base + i*16 (wave-uniform base).
__device__ inline void g2l16(const f16_t* g, f16_t* l) {
    auto gp = (const __attribute__((address_space(1))) uint32_t*)(uintptr_t)g;
    auto lp = (__attribute__((address_space(3))) uint32_t*)(uint32_t)(uintptr_t)l;
    __builtin_amdgcn_global_load_lds(gp, lp, 16, 0, 0);
}

// counted vmcnt wait, compile-time immediate, memory-clobbered.
template<int N> __device__ inline void vmwait() {
    static_assert(N == 0 || N == 2 || N == 4 || N == 6, "add vmcnt case");
    if constexpr (N == 0)      asm volatile("s_waitcnt vmcnt(0)" ::: "memory");
    else if constexpr (N == 2) asm volatile("s_waitcnt vmcnt(2)" ::: "memory");
    else if constexpr (N == 4) asm volatile("s_waitcnt vmcnt(4)" ::: "memory");
    else                       asm volatile("s_waitcnt vmcnt(6)" ::: "memory");
}

__device__ inline void barrier_mem() {
    asm volatile("s_barrier" ::: "memory");
    __builtin_amdgcn_sched_barrier(0);
}

// ---- XCD chunk swizzle (bijective; nwg % 8 == 0, pow2 chunks) ---------------
template<int CHX, int CHY>
__device__ inline void xcd_swizzle(int& bx, int& by, int& bz) {
    const int nbx = gridDim.x, nby = gridDim.y, nbz = gridDim.z;
    const int lin = ((int)blockIdx.z * nby + blockIdx.y) * nbx + blockIdx.x;
    const int nwg = nbx * nby * nbz;
    const int cpx = nwg >> 3;
    const int logical = (lin & 7) * cpx + (lin >> 3);
    constexpr int CHB = CHX * CHY;
    const int chunk  = logical / CHB;
    const int within = logical % CHB;
    const int cx = within % CHX, cy = within / CHX;
    const int chunks_x = nbx / CHX;
    const int chx = chunk % chunks_x;
    int tt = chunk / chunks_x;
    const int chunks_y = nby / CHY;
    bz = tt / chunks_y;
    by = (tt % chunks_y) * CHY + cy;
    bx = chx * CHX + cx;
}

// ---------------- stats: mean + rstd (unbiased var, ddof=1) per (b,c) --------
__global__ __launch_bounds__(256) void stats_kernel(
    const float* __restrict__ xc, const float* __restrict__ xs,
    float* __restrict__ meanc, float* __restrict__ rstdc,
    float* __restrict__ means, float* __restrict__ rstds)
{
    int id = blockIdx.x;
    int bc = id & 2047;
    const float4* x = (const float4*)((id < 2048 ? xc : xs) + (size_t)bc * HW_DIM);
    int tid = threadIdx.x;
    float s = 0.f, ss = 0.f;
#pragma unroll
    for (int i = 0; i < 4; i++) {
        float4 v = x[tid + (i << 8)];
        s += v.x + v.y + v.z + v.w;
        ss += v.x * v.x + v.y * v.y + v.z * v.z + v.w * v.w;
    }
#pragma unroll
    for (int o = 32; o; o >>= 1) { s += __shfl_down(s, o); ss += __shfl_down(ss, o); }
    __shared__ float red[8];
    if ((tid & 63) == 0) { red[(tid >> 6) * 2] = s; red[(tid >> 6) * 2 + 1] = ss; }
    __syncthreads();
    if (tid == 0) {
        s  = red[0] + red[2] + red[4] + red[6];
        ss = red[1] + red[3] + red[5] + red[7];
        float mean = s * (1.0f / 4096.0f);
        float var  = (ss - 4096.0f * mean * mean) * (1.0f / 4095.0f);
        float rstd = rsqrtf(var + 1e-5f);
        if (id < 2048) { meanc[bc] = mean; rstdc[bc] = rstd; }
        else           { means[bc] = mean; rstds[bc] = rstd; }
    }
}

// ---------------- weight pack: fp32 -> fp16 + bias copy ----------------------
__global__ __launch_bounds__(256) void pack_w4_kernel(
    const float* __restrict__ w0, const float* __restrict__ w1,
    const float* __restrict__ w2, const float* __restrict__ w3,
    f16_t* __restrict__ h0, f16_t* __restrict__ h1,
    f16_t* __restrict__ h2, f16_t* __restrict__ h3,
    const float* __restrict__ bb0, const float* __restrict__ bb1,
    const float* __restrict__ bb2, const float* __restrict__ bb3,
    float* __restrict__ biasws)
{
    int which = blockIdx.y;
    const float* w = which == 0 ? w0 : which == 1 ? w1 : which == 2 ? w2 : w3;
    f16_t* h = which == 0 ? h0 : which == 1 ? h1 : which == 2 ? h2 : h3;
    const float* bs = which == 0 ? bb0 : which == 1 ? bb1 : which == 2 ? bb2 : bb3;
    int i = blockIdx.x * 256 + threadIdx.x;
    h[i] = (f16_t)w[i];
    if (i < C_DIM) biasws[which * C_DIM + i] = bs[i];
}

// ---------------- input pack: (B,C,HW) fp32 -> (B,HW,C) fp16 -----------------
__global__ __launch_bounds__(256) void pack_T_kernel(
    const float* __restrict__ xc, const float* __restrict__ xs,
    const float* __restrict__ meanc, const float* __restrict__ rstdc,
    const float* __restrict__ means, const float* __restrict__ rstds,
    f16_t* __restrict__ ch, f16_t* __restrict__ sh, f16_t* __restrict__ sraw)
{
    __shared__ float tile[32][33];
    int z = blockIdx.z;
    int b = z & 3, src = z >> 2;
    const float* x    = (src == 0) ? xc : xs;
    const float* mean = (src == 0) ? meanc : means;
    const float* rstd = (src == 0) ? rstdc : rstds;

    int c0 = blockIdx.y * 32, p0 = blockIdx.x * 32;
    int tp = threadIdx.x & 31, tc8 = threadIdx.x >> 5;
    const float* xb = x + ((size_t)b * C_DIM + c0) * HW_DIM + p0;
#pragma unroll
    for (int it = 0; it < 4; it++) {
        int c = tc8 + it * 8;
        tile[c][tp] = xb[(size_t)c * HW_DIM + tp];
    }
    __syncthreads();
    int wc = threadIdx.x & 31, wp8 = threadIdx.x >> 5;
    float m = mean[b * C_DIM + c0 + wc];
    float r = rstd[b * C_DIM + c0 + wc];
    size_t obase = ((size_t)b * HW_DIM + p0) * C_DIM + c0;
    f16_t* ohb = ((src == 0) ? ch : sh) + obase;
    f16_t* srb = sraw + obase;
#pragma unroll
    for (int it = 0; it < 4; it++) {
        int p = wp8 + it * 8;
        float v = tile[wc][p];
        ohb[(size_t)p * C_DIM + wc] = (f16_t)((v - m) * r);
        if (src == 1) srb[(size_t)p * C_DIM + wc] = (f16_t)v;
    }
}

// ---------------- row softmax: S fp32 (4096x4096) -> P fp16, normalized ------
__global__ __launch_bounds__(256) void softmax_rows(
    const float* __restrict__ S, f16_t* __restrict__ P)
{
    int row = blockIdx.x;
    int tid = threadIdx.x;
    int wave = tid >> 6, lane = tid & 63;
    const float4* sr = (const float4*)(S + (size_t)row * HW_DIM);
    float4 v[4];
    float mx = -3.4e38f;
#pragma unroll
    for (int i = 0; i < 4; i++) {
        v[i] = sr[tid + (i << 8)];
        mx = fmaxf(mx, fmaxf(fmaxf(v[i].x, v[i].y), fmaxf(v[i].z, v[i].w)));
    }
#pragma unroll
    for (int o = 32; o; o >>= 1) mx = fmaxf(mx, __shfl_down(mx, o));
    __shared__ float red[4];
    if (lane == 0) red[wave] = mx;
    __syncthreads();
    mx = fmaxf(fmaxf(red[0], red[1]), fmaxf(red[2], red[3]));
    float sum = 0.f;
#pragma unroll
    for (int i = 0; i < 4; i++) {
        v[i].x = __expf(v[i].x - mx); v[i].y = __expf(v[i].y - mx);
        v[i].z = __expf(v[i].z - mx); v[i].w = __expf(v[i].w - mx);
        sum += v[i].x + v[i].y + v[i].z + v[i].w;
    }
#pragma unroll
    for (int o = 32; o; o >>= 1) sum += __shfl_down(sum, o);
    __syncthreads();
    if (lane == 0) red[wave] = sum;
    __syncthreads();
    sum = red[0] + red[1] + red[2] + red[3];
    float inv = 1.0f / sum;
    uint2* pr = (uint2*)(P + (size_t)row * HW_DIM);
#pragma unroll
    for (int i = 0; i < 4; i++) {
        union { uint2 u; f16_t h[4]; } o;
        o.h[0] = (f16_t)(v[i].x * inv); o.h[1] = (f16_t)(v[i].y * inv);
        o.h[2] = (f16_t)(v[i].z * inv); o.h[3] = (f16_t)(v[i].w * inv);
        pr[tid + (i << 8)] = o.u;
    }
}

// ---------------- split-K reduce: frsT[q][c] = f16(sum of 4 fp32 partials) ---
__global__ __launch_bounds__(256) void reduce4_kernel(
    const float* __restrict__ part, f16_t* __restrict__ out)
{
    size_t i = (size_t)blockIdx.x * 256 + threadIdx.x;   // float4 index
    const float4* p0 = (const float4*)part;
    const float4* p1 = (const float4*)(part + CHW);
    const float4* p2 = (const float4*)(part + 2 * CHW);
    const float4* p3 = (const float4*)(part + 3 * CHW);
    float4 a = p0[i], b = p1[i], c = p2[i], d = p3[i];
    union { uint2 u; f16_t h[4]; } o;
    o.h[0] = (f16_t)(a.x + b.x + c.x + d.x);
    o.h[1] = (f16_t)(a.y + b.y + c.y + d.y);
    o.h[2] = (f16_t)(a.z + b.z + c.z + d.z);
    o.h[3] = (f16_t)(a.w + b.w + c.w + d.w);
    ((uint2*)out)[i] = o.u;
}

// ============ Engine A: gemm256d -- 256x256 dbuf-2 deep pipeline =============
// BM=BN=256, BK=64, 512 threads = 8 waves (2M x 4N), wave tile 128x64,
// acc[8][4]. LDS: 8 units of 128x64 f16 (16KB), idx = (t&1)*4 + isB*2 + h.
// Tile t phases (ks,nh), 16 MFMA each between 2 barriers:
//   p0: reads a[8],b0,b1; stage Bh0(t+1)
//   p1: reads b2,b3;      stage Bh1(t+1)
//   p2: reads a[8],b0,b1
//   p3: reads b2,b3;      stage Ah0,Ah1(t+2); MFMA; vmwait(4); barrier
// vmwait(4): forces tile t+1's 8 loads landed, A(t+2)'s 4 stay in flight.
// T2 swizzle: LDS granule g holds src granule g^(row&7) via pre-swizzled
// global source (linear g2l16 dest); reads XOR granule by fr&7.
template<int EPI, bool QK, int NT, int CHX, int CHY>
__global__ __launch_bounds__(512, 2) void gemm256d(
    const f16_t* __restrict__ Ah, const f16_t* __restrict__ Bh,
    void* __restrict__ Cout0, const float* __restrict__ bias,
    const float* __restrict__ resid,
    int lda, int ldc,
    long sAz, long sBz, long sCz, long sRz, long sAw, long sBw, long sCw)
{
    constexpr int UNIT = 128 * 64;                   // 8192 f16 = 16 KB
    __shared__ __align__(16) f16_t smem[8 * UNIT];   // 128 KB

    int bx, by, bz;
    xcd_swizzle<CHX, CHY>(bx, by, bz);

    const int tid  = threadIdx.x;
    const int wave = tid >> 6, lane = tid & 63;
    const int wm = (wave >> 2) * 128;
    const int wn = (wave & 3) * 64;
    const int fr = lane & 15;
    const int g16 = lane >> 4;
    const int key = fr & 7;
    const int ha  = wave >> 2;
    const int hb  = wn >> 7;
    const int rB  = wn - hb * 128;

    const int z   = QK ? (bz & 3) : bz;
    const int sel = QK ? (bz >> 2) : 0;
    const f16_t* Az = Ah + (size_t)z * sAz + (size_t)sel * sAw;
    const f16_t* Bz = Bh + (size_t)z * sBz + (size_t)sel * sBw;
    const float* biasp = bias ? (bias + (QK ? sel * C_DIM : 0)) : nullptr;
    const long mBlock = (long)by * 256;
    const long nBlock = (long)bx * 256;

    const int srow8 = lane >> 3;
    const int gsrc  = ((lane & 7) ^ srow8) * 8;
    const f16_t* aRow[2][2]; const f16_t* bRow[2][2];
#pragma unroll
    for (int h = 0; h < 2; h++)
#pragma unroll
        for (int q = 0; q < 2; q++) {
            long r = q * 64 + wave * 8 + srow8;
            aRow[h][q] = Az + (size_t)(mBlock + h * 128 + r) * lda + gsrc;
            bRow[h][q] = Bz + (size_t)(nBlock + h * 128 + r) * lda + gsrc;
        }
    const int dst0 = wave * 512;
    const int dst1 = 4096 + wave * 512;

    auto stageU = [&](int t, int isB, int h) {
        f16_t* ub = smem + ((t & 1) * 4 + isB * 2 + h) * UNIT;
        const long k0 = (long)t * 64;
        if (isB) {
            g2l16(bRow[h][0] + k0, ub + dst0);
            g2l16(bRow[h][1] + k0, ub + dst1);
        } else {
            g2l16(aRow[h][0] + k0, ub + dst0);
            g2l16(aRow[h][1] + k0, ub + dst1);
        }
    };

    f32x4 acc[8][4];
#pragma unroll
    for (int i = 0; i < 8; i++)
#pragma unroll
        for (int j = 0; j < 4; j++) acc[i][j] = (f32x4){0.f, 0.f, 0.f, 0.f};

    // prologue: tile 0 (8 loads) + A(1) (4 loads); wait tile 0, A(1) in flight
    stageU(0, 0, 0); stageU(0, 0, 1); stageU(0, 1, 0); stageU(0, 1, 1);
    if (NT > 1) { stageU(1, 0, 0); stageU(1, 0, 1); }
    vmwait<4>();
    barrier_mem();

#pragma unroll
    for (int t = 0; t < NT; ++t) {
        const f16_t* bufA = smem + ((t & 1) * 4 + ha) * UNIT;
        const f16_t* bufB = smem + ((t & 1) * 4 + 2 + hb) * UNIT;
#pragma unroll
        for (int ks = 0; ks < 2; ++ks) {
            const int gr = ((ks * 4 + g16) ^ key) * 8;
            f16x8 a[8], b0, b1;
            // ---- phase nh=0: a[8] + b0,b1 ----
#pragma unroll
            for (int mi = 0; mi < 8; mi++)
                a[mi] = *reinterpret_cast<const f16x8*>(
                    bufA + (mi * 16 + fr) * 64 + gr);
            b0 = *reinterpret_cast<const f16x8*>(bufB + (rB + fr) * 64 + gr);
            b1 = *reinterpret_cast<const f16x8*>(bufB + (rB + 16 + fr) * 64 + gr);
            if (ks == 0 && t + 1 < NT) stageU(t + 1, 1, 0);      // p0: Bh0(t+1)
            barrier_mem();
            __builtin_amdgcn_s_setprio(1);
#pragma unroll
            for (int mi = 0; mi < 8; mi++) {
                acc[mi][0] = mfma_f16(a[mi], b0, acc[mi][0]);
                acc[mi][1] = mfma_f16(a[mi], b1, acc[mi][1]);
            }
            __builtin_amdgcn_s_setprio(0);
            barrier_mem();
            // ---- phase nh=1: b2,b3 (reuse a[8]) ----
            b0 = *reinterpret_cast<const f16x8*>(bufB + (rB + 32 + fr) * 64 + gr);
            b1 = *reinterpret_cast<const f16x8*>(bufB + (rB + 48 + fr) * 64 + gr);
            if (ks == 0) {
                if (t + 1 < NT) stageU(t + 1, 1, 1);             // p1: Bh1(t+1)
            } else {
                if (t + 2 < NT) { stageU(t + 2, 0, 0); stageU(t + 2, 0, 1); } // p3: A(t+2)
            }
            barrier_mem();
            __builtin_amdgcn_s_setprio(1);
#pragma unroll
            for (int mi = 0; mi < 8; mi++) {
                acc[mi][2] = mfma_f16(a[mi], b0, acc[mi][2]);
                acc[mi][3] = mfma_f16(a[mi], b1, acc[mi][3]);
            }
            __builtin_amdgcn_s_setprio(0);
            if (ks == 1) {
                if (t + 2 < NT)      vmwait<4>();  // tile t+1 landed, A(t+2) in flight
                else if (t + 1 < NT) vmwait<0>();  // drain for last tile
            }
            barrier_mem();
        }
    }

    // epilogue. D layout: col(n)=lane&15, row(m)=(lane>>4)*4+reg
    const int col  = lane & 15;
    const int rowq = (lane >> 4) * 4;
    const size_t cbase = (size_t)z * sCz + (size_t)sel * sCw;
#pragma unroll
    for (int mi = 0; mi < 8; mi++) {
        const long mb = mBlock + wm + mi * 16 + rowq;
        float bv[4];
#pragma unroll
        for (int r = 0; r < 4; r++) bv[r] = biasp ? biasp[mb + r] : 0.0f;
#pragma unroll
        for (int j2 = 0; j2 < 4; j2++) {
            const long n = nBlock + wn + j2 * 16 + col;
            float v[4];
#pragma unroll
            for (int r = 0; r < 4; r++) v[r] = acc[mi][j2][r] + bv[r];
            if constexpr (EPI == 0) {
                float* O = (float*)Cout0 + cbase;
                const float* R = resid ? (resid + (size_t)z * sRz) : nullptr;
#pragma unroll
                for (int r = 0; r < 4; r++) {
                    size_t off = (size_t)(mb + r) * ldc + n;
                    O[off] = v[r] + (R ? R[off] : 0.0f);
                }
            } else if constexpr (EPI == 1) {
                f16_t* O = (f16_t*)Cout0 + cbase;
#pragma unroll
                for (int r = 0; r < 4; r++) O[(size_t)(mb + r) * ldc + n] = (f16_t)v[r];
            } else if constexpr (EPI == 3) {
                alignas(8) f16_t h[4];
#pragma unroll
                for (int r = 0; r < 4; r++) h[r] = (f16_t)v[r];
                *reinterpret_cast<uint2*>((f16_t*)Cout0 + cbase + (size_t)n * ldc + mb)
                    = *reinterpret_cast<uint2*>(h);
            } else {
                alignas(16) float h[4];
#pragma unroll
                for (int r = 0; r < 4; r++) h[r] = v[r];
                *reinterpret_cast<float4*>((float*)Cout0 + cbase + (size_t)n * ldc + mb)
                    = *reinterpret_cast<float4*>(h);
            }
        }
    }
}

// ============ Engine B: gemm128r -- BN=128 ring-3 (R11, verified) ============
// BM=256, BN=128, BK=64, 512 threads (8 waves 2Mx4N, wave tile 128x32,
// acc[8][2]). Ring-3 LDS 144KB; per tile 2 phases; stage A(t+2) at ks=0,
// B(t+2) at ks=1; vmcnt(6) counted once per tile.
template<int EPI, bool QK, int NT, int CHX, int CHY>
__global__ __launch_bounds__(512, 2) void gemm128r(
    const f16_t* __restrict__ Ah, const f16_t* __restrict__ Bh,
    void* __restrict__ Cout0, const float* __restrict__ bias,
    const float* __restrict__ resid,
    int lda, int ldc,
    long sAz, long sBz, long sCz, long sRz, long sAw, long sBw, long sCw)
{
    constexpr int AE = 256 * 64;
    constexpr int BE = 128 * 64;
    constexpr int BUFE = AE + BE;
    __shared__ __align__(16) f16_t smem[3 * BUFE];   // 144KB

    int bx, by, bz;
    xcd_swizzle<CHX, CHY>(bx, by, bz);

    const int tid  = threadIdx.x;
    const int wave = tid >> 6, lane = tid & 63;
    const int wm = (wave >> 2) * 128;
    const int wn = (wave & 3) * 32;
    const int fr = lane & 15;
    const int g16 = lane >> 4;
    const int key = fr & 7;

    const int z   = QK ? (bz & 3) : bz;
    const int sel = QK ? (bz >> 2) : 0;
    const f16_t* Az = Ah + (size_t)z * sAz + (size_t)sel * sAw;
    const f16_t* Bz = Bh + (size_t)z * sBz + (size_t)sel * sBw;
    const float* biasp = bias ? (bias + (QK ? sel * C_DIM : 0)) : nullptr;
    const long mBlock = (long)by * 256;
    const long nBlock = (long)bx * 128;

    const int srow8 = lane >> 3;
    const int gsrc  = ((lane & 7) ^ srow8) * 8;
    const f16_t* aSrc[4]; const f16_t* bSrc[2];
    int aDst[4], bDst[2];
#pragma unroll
    for (int q = 0; q < 4; q++) {
        int j = 4 * wave + q;
        aSrc[q] = Az + (size_t)(mBlock + 8 * j + srow8) * lda + gsrc;
        aDst[q] = j * 512;
    }
#pragma unroll
    for (int q = 0; q < 2; q++) {
        int j = 2 * wave + q;
        bSrc[q] = Bz + (size_t)(nBlock + 8 * j + srow8) * lda + gsrc;
        bDst[q] = AE + j * 512;
    }

    auto stageA = [&](int t) {
        f16_t* dst = smem + (t % 3) * BUFE;
        const int k0 = t * 64;
#pragma unroll
        for (int q = 0; q < 4; q++) g2l16(aSrc[q] + k0, dst + aDst[q]);
    };
    auto stageB = [&](int t) {
        f16_t* dst = smem + (t % 3) * BUFE;
        const int k0 = t * 64;
#pragma unroll
        for (int q = 0; q < 2; q++) g2l16(bSrc[q] + k0, dst + bDst[q]);
    };

    f32x4 acc[8][2];
#pragma unroll
    for (int i = 0; i < 8; i++)
#pragma unroll
        for (int j = 0; j < 2; j++) acc[i][j] = (f32x4){0.f, 0.f, 0.f, 0.f};

    stageA(0); stageB(0); stageA(1); stageB(1);
    vmwait<6>();
    barrier_mem();

#pragma unroll
    for (int t = 0; t < NT; ++t) {
        const f16_t* buf = smem + (t % 3) * BUFE;
#pragma unroll
        for (int ks = 0; ks < 2; ++ks) {
            f16x8 a[8], b0, b1;
            const int gr = ((ks * 4 + g16) ^ key) * 8;
#pragma unroll
            for (int mi = 0; mi < 8; mi++)
                a[mi] = *reinterpret_cast<const f16x8*>(
                    buf + (wm + mi * 16 + fr) * 64 + gr);
            b0 = *reinterpret_cast<const f16x8*>(buf + AE + (wn + fr) * 64 + gr);
            b1 = *reinterpret_cast<const f16x8*>(buf + AE + (wn + 16 + fr) * 64 + gr);
            if (t + 2 < NT) { if (ks == 0) stageA(t + 2); else stageB(t + 2); }
            if (ks == 1) {
                if (t + 2 < NT)      vmwait<6>();
                else if (t + 1 < NT) vmwait<0>();
            }
            barrier_mem();
            __builtin_amdgcn_s_setprio(1);
#pragma unroll
            for (int mi = 0; mi < 8; mi++) {
                acc[mi][0] = mfma_f16(a[mi], b0, acc[mi][0]);
                acc[mi][1] = mfma_f16(a[mi], b1, acc[mi][1]);
            }
            __builtin_amdgcn_s_setprio(0);
            barrier_mem();
        }
    }

    const int col  = lane & 15;
    const int rowq = (lane >> 4) * 4;
    const size_t cbase = (size_t)z * sCz + (size_t)sel * sCw;
#pragma unroll
    for (int mi = 0; mi < 8; mi++) {
        const long mb = mBlock + wm + mi * 16 + rowq;
        float bv[4];
#pragma unroll
        for (int r = 0; r < 4; r++) bv[r] = biasp ? biasp[mb + r] : 0.0f;
#pragma unroll
        for (int j2 = 0; j2 < 2; j2++) {
            const long n = nBlock + wn + j2 * 16 + col;
            float v[4];
#pragma unroll
            for (int r = 0; r < 4; r++) v[r] = acc[mi][j2][r] + bv[r];
            if constexpr (EPI == 0) {
                float* O = (float*)Cout0 + cbase;
                const float* R = resid ? (resid + (size_t)z * sRz) : nullptr;
#pragma unroll
                for (int r = 0; r < 4; r++) {
                    size_t off = (size_t)(mb + r) * ldc + n;
                    O[off] = v[r] + (R ? R[off] : 0.0f);
                }
            } else if constexpr (EPI == 1) {
                f16_t* O = (f16_t*)Cout0 + cbase;
#pragma unroll
                for (int r = 0; r < 4; r++) O[(size_t)(mb + r) * ldc + n] = (f16_t)v[r];
            } else if constexpr (EPI == 3) {
                alignas(8) f16_t h[4];
#pragma unroll
                for (int r = 0; r < 4; r++) h[r] = (f16_t)v[r];
                *reinterpret_cast<uint2*>((f16_t*)Cout0 + cbase + (size_t)n * ldc + mb)
                    = *reinterpret_cast<uint2*>(h);
            } else {
                alignas(16) float h[4];
#pragma unroll
                for (int r = 0; r < 4; r++) h[r] = v[r];
                *reinterpret_cast<float4*>((float*)Cout0 + cbase + (size_t)n * ldc + mb)
                    = *reinterpret_cast<float4*>(h);
            }
        }
    }
}

// ---------------------------------------------------------------------------
extern "C" void kernel_launch(void* const* d_in, const int* in_sizes, int n_in,
                              void* d_out, int out_size, void* d_ws, size_t ws_size,
                              hipStream_t stream)
{
    const float* x_fcc = (const float*)d_in[0];
    const float* x_fss = (const float*)d_in[1];
    const float* w1 = (const float*)d_in[2];
    const float* b1 = (const float*)d_in[3];
    const float* w2 = (const float*)d_in[4];
    const float* b2 = (const float*)d_in[5];
    const float* w3 = (const float*)d_in[6];
    const float* b3 = (const float*)d_in[7];
    const float* wrs = (const float*)d_in[8];
    const float* brs = (const float*)d_in[9];
    float* out = (float*)d_out;
    (void)n_in; (void)in_sizes; (void)out_size; (void)ws_size;

    char* base = (char*)d_ws;
    size_t off = 0;
    auto take = [&](size_t bytes) -> char* {
        char* p = base + off;
        off += (bytes + 255) & ~(size_t)255;
        return p;
    };
    const size_t WB = (size_t)C_DIM * C_DIM * sizeof(f16_t);    // 512 KB
    const size_t TB = (size_t)NBATCH * CHW * sizeof(f16_t);     // 16 MB
    const long  TBe = NBATCH * CHW;                             // 8388608 elems

    float* meanc = (float*)take(2048 * 4);
    float* rstdc = (float*)take(2048 * 4);
    float* means = (float*)take(2048 * 4);
    float* rstds = (float*)take(2048 * 4);
    float* biasws = (float*)take(4 * C_DIM * 4);
    f16_t* w1h = (f16_t*)take(WB);
    f16_t* w2h = (f16_t*)take(WB);
    f16_t* w3h = (f16_t*)take(WB);
    f16_t* wrh = (f16_t*)take(WB);
    f16_t* qT = (f16_t*)take(TB);
    f16_t* kT = (f16_t*)take(TB);
    f16_t* vh   = (f16_t*)take(TB);
    f16_t* frsT = (f16_t*)take(TB);
    // 128 MB region. phase-1: xcT(16) xsT(16) xsrT(16) [dead after convs].
    // per-batch: S fp32 [0,64) -> P fp16 [64,96) -> partials fp32 [96,128).
    char* packb = take(8 * TB);
    f16_t* xcT  = (f16_t*)(packb);
    f16_t* xsT  = (f16_t*)(packb + TB);
    f16_t* xsrT = (f16_t*)(packb + 2 * TB);
    float* Smat = (float*)(packb);
    f16_t* Pmat = (f16_t*)(packb + 4 * TB);
    float* Part = (float*)(packb + 6 * TB);
    // total ws unchanged (~194 MB)

    dim3 blk(256);
    dim3 blk5(512);

    // 1. stats
    stats_kernel<<<dim3(4096), blk, 0, stream>>>(x_fcc, x_fss, meanc, rstdc, means, rstds);
    // 2. weight packs + bias copy
    pack_w4_kernel<<<dim3(1024, 4), blk, 0, stream>>>(
        w1, w2, w3, wrs, w1h, w2h, w3h, wrh, b1, b2, b3, brs, biasws);
    // 3. input packs (single style read -> sh + sraw)
    pack_T_kernel<<<dim3(128, 16, 8), blk, 0, stream>>>(
        x_fcc, x_fss, meanc, rstdc, means, rstds, xcT, xsT, xsrT);
    // 4. q+k convs merged (engine A, 256 blocks): sel0=(w1,content)->qT; 1->kT
    gemm256d<3, true, 8, 8, 2><<<dim3(16, 2, 8), blk5, 0, stream>>>(
        w1h, xcT, qT, biasws, nullptr, C_DIM, C_DIM,
        0L, CHW, CHW, 0L, (long)C_DIM * C_DIM, TBe, TBe);
    // 5. v conv (engine B, 256 blocks): vh[c][p] f16 +bias
    gemm128r<1, false, 8, 8, 2><<<dim3(32, 2, 4), blk5, 0, stream>>>(
        w3h, xsrT, vh, biasws + 2 * C_DIM, nullptr, C_DIM, HW_DIM,
        0L, CHW, CHW, 0L, 0L, 0L, 0L);
    // 6. per-batch attention
    for (int b = 0; b < NBATCH; b++) {
        // scores: S[q][k] fp32 (engine A, 256 blocks = 1/CU)
        gemm256d<0, false, 8, 4, 8><<<dim3(16, 16, 1), blk5, 0, stream>>>(
            qT + (size_t)b * CHW, kT + (size_t)b * CHW,
            Smat, nullptr, nullptr, C_DIM, HW_DIM,
            0L, 0L, 0L, 0L, 0L, 0L, 0L);
        softmax_rows<<<dim3(4096), blk, 0, stream>>>(Smat, Pmat);
        // PV split-4 (engine B, 256 blocks): partial[z] fp32 [q][c]
        gemm128r<4, false, 16, 8, 2><<<dim3(32, 2, 4), blk5, 0, stream>>>(
            vh + (size_t)b * CHW, Pmat,
            Part, nullptr, nullptr, HW_DIM, C_DIM,
            1024L, 1024L, CHW, 0L, 0L, 0L, 0L);
        // reduce 4 partials -> fp16 frsT[b]
        reduce4_kernel<<<dim3(CHW / 1024), blk, 0, stream>>>(
            Part, frsT + (size_t)b * CHW);
    }
    // 7. final conv + bias + residual -> fp32 out (engine B, 256 blocks)
    gemm128r<0, false, 8, 8, 2><<<dim3(32, 2, 4), blk5, 0, stream>>>(
        wrh, frsT, out, biasws + 3 * C_DIM, x_fcc, C_DIM, HW_DIM,
        0L, CHW, CHW, CHW, 0L, 0L, 0L);
}